// Round 3
// baseline (790.979 us; speedup 1.0000x reference)
//
#include <hip/hip_runtime.h>
#include <hip/hip_bf16.h>

#define NN 100000
#define NE 800000
#define DIM 512
#define BM 128
#define BN 128
#define BK 32
#define LDT 40   // padded LDS stride in bf16 elems (80 B: 16B-aligned, conflict-free)

static constexpr int NB_SCAN = (NN + 255) / 256;   // 391

typedef __attribute__((ext_vector_type(4))) float f32x4;
typedef __bf16 bf16x8 __attribute__((ext_vector_type(8)));

static __device__ __forceinline__ ushort f2bf(float f) {
    __bf16 h = (__bf16)f;
    return __builtin_bit_cast(ushort, h);
}
static __device__ __forceinline__ float bflo(unsigned u) {
    return __builtin_bit_cast(float, u << 16);
}
static __device__ __forceinline__ float bfhi(unsigned u) {
    return __builtin_bit_cast(float, u & 0xffff0000u);
}

// ---------------- prep kernels ----------------

__global__ __launch_bounds__(256) void wt_convert(const float* __restrict__ W,
                                                  ushort* __restrict__ WT) {
    int idx = blockIdx.x * 256 + threadIdx.x;     // 262144 total
    int n = idx & (DIM - 1);
    int k = idx >> 9;
    WT[(size_t)n * DIM + k] = f2bf(W[(size_t)k * DIM + n]);
}

__global__ __launch_bounds__(256) void bn_prep(const float* __restrict__ B,
                                               const float* __restrict__ G,
                                               const float* __restrict__ BE,
                                               const float* __restrict__ RM,
                                               const float* __restrict__ RV,
                                               float* __restrict__ cscale,
                                               float* __restrict__ cbias) {
    int c = blockIdx.x * 256 + threadIdx.x;
    if (c < DIM) {
        float s = G[c] * rsqrtf(RV[c] + 1e-5f);
        cscale[c] = s;
        cbias[c] = (B[c] - RM[c]) * s + BE[c];
    }
}

// ---------------- degree / CSR build ----------------
// edge_index is staged by the harness as int32 (integer -> const int*).

__global__ __launch_bounds__(256) void deg_count(const int* __restrict__ EI,
                                                 int* __restrict__ cnt) {
    int e = blockIdx.x * 256 + threadIdx.x;
    if (e < NE) {
        int d = EI[NE + e];
        if (d >= 0 && d < NN) atomicAdd(&cnt[d], 1);
    }
}

__global__ __launch_bounds__(256) void dis_kernel(const int* __restrict__ cnt,
                                                  float* __restrict__ dis) {
    int v = blockIdx.x * 256 + threadIdx.x;
    if (v < NN) dis[v] = rsqrtf(1.0f + (float)cnt[v]);
}

__global__ __launch_bounds__(256) void scan1(const int* __restrict__ cnt,
                                             int* __restrict__ bsum) {
    __shared__ int sd[256];
    int i = blockIdx.x * 256 + threadIdx.x;
    int v = (i < NN) ? cnt[i] : 0;
    sd[threadIdx.x] = v;
    __syncthreads();
    for (int off = 128; off > 0; off >>= 1) {
        if (threadIdx.x < off) sd[threadIdx.x] += sd[threadIdx.x + off];
        __syncthreads();
    }
    if (threadIdx.x == 0) bsum[blockIdx.x] = sd[0];
}

__global__ __launch_bounds__(512) void scan2(const int* __restrict__ bsum,
                                             int* __restrict__ bpre) {
    __shared__ int s[2][512];
    int t = threadIdx.x;
    int v = (t < NB_SCAN) ? bsum[t] : 0;
    s[0][t] = v;
    __syncthreads();
    int cur = 0;
    for (int off = 1; off < 512; off <<= 1) {
        int x = s[cur][t];
        if (t >= off) x += s[cur][t - off];
        s[cur ^ 1][t] = x;
        cur ^= 1;
        __syncthreads();
    }
    if (t < NB_SCAN) bpre[t] = s[cur][t] - v;   // exclusive prefix of block sums
}

__global__ __launch_bounds__(256) void scan3(const int* __restrict__ cnt,
                                             const int* __restrict__ bpre,
                                             int* __restrict__ offs) {
    __shared__ int s[2][256];
    int t = threadIdx.x;
    int i = blockIdx.x * 256 + t;
    int v = (i < NN) ? cnt[i] : 0;
    s[0][t] = v;
    __syncthreads();
    int cur = 0;
    for (int off = 1; off < 256; off <<= 1) {
        int x = s[cur][t];
        if (t >= off) x += s[cur][t - off];
        s[cur ^ 1][t] = x;
        cur ^= 1;
        __syncthreads();
    }
    if (i < NN) offs[i] = bpre[blockIdx.x] + s[cur][t] - v;   // exclusive
}

__global__ __launch_bounds__(256) void edge_scatter(const int* __restrict__ EI,
                                                    const int* __restrict__ offs,
                                                    int* __restrict__ cursor,
                                                    const float* __restrict__ dis,
                                                    int* __restrict__ srcs,
                                                    float* __restrict__ norms) {
    int e = blockIdx.x * 256 + threadIdx.x;
    if (e >= NE) return;
    int s = EI[e];
    int d = EI[NE + e];
    if (s < 0 || s >= NN || d < 0 || d >= NN) return;
    int pos = offs[d] + atomicAdd(&cursor[d], 1);
    srcs[pos] = s;
    norms[pos] = dis[s] * dis[d];
}

// ---------------- GEMM: H(bf16) = X(fp32) @ W ----------------
// WT is W^T (bf16, [out=512][in=512]) so both MFMA operands are K-contiguous.

__global__ __launch_bounds__(256) void gemm_xw(const float* __restrict__ X,
                                               const ushort* __restrict__ WT,
                                               ushort* __restrict__ H) {
    __shared__ ushort As[BM * LDT];
    __shared__ ushort Bs[BN * LDT];
    const int tid = threadIdx.x;
    const int brow = blockIdx.y * BM;
    const int bcol = blockIdx.x * BN;
    const int lane = tid & 63;
    const int wave = tid >> 6;
    const int wr = wave >> 1, wc = wave & 1;

    f32x4 acc[4][4];
    #pragma unroll
    for (int m = 0; m < 4; ++m)
        #pragma unroll
        for (int n = 0; n < 4; ++n) {
            f32x4 z = {0.f, 0.f, 0.f, 0.f};
            acc[m][n] = z;
        }

    const int ag = tid & 7;    // k-group of 4 floats for A staging
    const int ar = tid >> 3;   // 0..31
    const int bg = tid & 3;    // k-group of 8 bf16 for B staging
    const int br = tid >> 2;   // 0..63

    for (int kt = 0; kt < DIM; kt += BK) {
        #pragma unroll
        for (int p = 0; p < 4; ++p) {
            int row = p * 32 + ar;
            int grow = brow + row;
            float4 v = make_float4(0.f, 0.f, 0.f, 0.f);
            if (grow < NN) v = *(const float4*)(X + (size_t)grow * DIM + kt + ag * 4);
            ushort4 w;
            w.x = f2bf(v.x); w.y = f2bf(v.y); w.z = f2bf(v.z); w.w = f2bf(v.w);
            *(ushort4*)&As[row * LDT + ag * 4] = w;
        }
        #pragma unroll
        for (int p = 0; p < 2; ++p) {
            int row = p * 64 + br;
            uint4 v = *(const uint4*)(WT + (size_t)(bcol + row) * DIM + kt + bg * 8);
            *(uint4*)&Bs[row * LDT + bg * 8] = v;
        }
        __syncthreads();

        bf16x8 af[4], bfr[4];
        const int kg = (lane >> 4) * 8;
        const int rl = lane & 15;
        #pragma unroll
        for (int m = 0; m < 4; ++m)
            af[m] = *(const bf16x8*)&As[(wr * 64 + m * 16 + rl) * LDT + kg];
        #pragma unroll
        for (int n = 0; n < 4; ++n)
            bfr[n] = *(const bf16x8*)&Bs[(wc * 64 + n * 16 + rl) * LDT + kg];
        #pragma unroll
        for (int m = 0; m < 4; ++m)
            #pragma unroll
            for (int n = 0; n < 4; ++n)
                acc[m][n] = __builtin_amdgcn_mfma_f32_16x16x32_bf16(af[m], bfr[n], acc[m][n], 0, 0, 0);
        __syncthreads();
    }

    // C/D layout: col = lane&15, row = (lane>>4)*4 + reg  [m89-verified]
    const int rb = (lane >> 4) * 4;
    const int cl = lane & 15;
    #pragma unroll
    for (int m = 0; m < 4; ++m) {
        #pragma unroll
        for (int n = 0; n < 4; ++n) {
            int col = bcol + wc * 64 + n * 16 + cl;
            #pragma unroll
            for (int r = 0; r < 4; ++r) {
                int row = brow + wr * 64 + m * 16 + rb + r;
                if (row < NN) H[(size_t)row * DIM + col] = f2bf(acc[m][n][r]);
            }
        }
    }
}

// ---------------- aggregation + self-loop + bias + BN + ReLU ----------------
// One wave per node; lane owns cols [lane*8, lane*8+8).

__global__ __launch_bounds__(256) void aggregate(const ushort* __restrict__ H,
                                                 const int* __restrict__ srcs,
                                                 const float* __restrict__ norms,
                                                 const int* __restrict__ offs,
                                                 const int* __restrict__ cnt,
                                                 const float* __restrict__ dis,
                                                 const float* __restrict__ cscale,
                                                 const float* __restrict__ cbias,
                                                 float* __restrict__ out) {
    const int v = (blockIdx.x * 256 + threadIdx.x) >> 6;
    if (v >= NN) return;
    const int lane = threadIdx.x & 63;
    const size_t lo8 = (size_t)(lane << 3);

    float acc[8] = {0.f, 0.f, 0.f, 0.f, 0.f, 0.f, 0.f, 0.f};
    const int start = offs[v];
    const int ecnt = cnt[v];
    for (int e = 0; e < ecnt; ++e) {
        const int s = srcs[start + e];
        const float nm = norms[start + e];
        uint4 pk = *(const uint4*)(H + (size_t)s * DIM + lo8);
        acc[0] += nm * bflo(pk.x); acc[1] += nm * bfhi(pk.x);
        acc[2] += nm * bflo(pk.y); acc[3] += nm * bfhi(pk.y);
        acc[4] += nm * bflo(pk.z); acc[5] += nm * bfhi(pk.z);
        acc[6] += nm * bflo(pk.w); acc[7] += nm * bfhi(pk.w);
    }
    {   // self-loop: + h[v] * dis[v]^2
        const float dv = dis[v];
        const float sw = dv * dv;
        uint4 pk = *(const uint4*)(H + (size_t)v * DIM + lo8);
        acc[0] += sw * bflo(pk.x); acc[1] += sw * bfhi(pk.x);
        acc[2] += sw * bflo(pk.y); acc[3] += sw * bfhi(pk.y);
        acc[4] += sw * bflo(pk.z); acc[5] += sw * bfhi(pk.z);
        acc[6] += sw * bflo(pk.w); acc[7] += sw * bfhi(pk.w);
    }
    const int c0 = lane << 3;
    float4 s0 = *(const float4*)(cscale + c0);
    float4 s1 = *(const float4*)(cscale + c0 + 4);
    float4 b0 = *(const float4*)(cbias + c0);
    float4 b1 = *(const float4*)(cbias + c0 + 4);
    float4 o0, o1;
    o0.x = fmaxf(0.f, acc[0] * s0.x + b0.x);
    o0.y = fmaxf(0.f, acc[1] * s0.y + b0.y);
    o0.z = fmaxf(0.f, acc[2] * s0.z + b0.z);
    o0.w = fmaxf(0.f, acc[3] * s0.w + b0.w);
    o1.x = fmaxf(0.f, acc[4] * s1.x + b1.x);
    o1.y = fmaxf(0.f, acc[5] * s1.y + b1.y);
    o1.z = fmaxf(0.f, acc[6] * s1.z + b1.z);
    o1.w = fmaxf(0.f, acc[7] * s1.w + b1.w);
    *(float4*)(out + (size_t)v * DIM + c0) = o0;
    *(float4*)(out + (size_t)v * DIM + c0 + 4) = o1;
}

// ---------------- launch ----------------

// workspace layout (bytes)
static constexpr size_t OFF_H    = 0;                           // 100000*512*2 = 102,400,000
static constexpr size_t OFF_WT   = OFF_H + 102400000;           // 512*512*2    = 524,288
static constexpr size_t OFF_CNT  = OFF_WT + 524288;             // 400,000
static constexpr size_t OFF_DIS  = OFF_CNT + 400000;            // 400,000
static constexpr size_t OFF_OFFS = OFF_DIS + 400000;            // 400,000
static constexpr size_t OFF_CUR  = OFF_OFFS + 400000;           // 400,000
static constexpr size_t OFF_BSUM = OFF_CUR + 400000;            // 4,096
static constexpr size_t OFF_BPRE = OFF_BSUM + 4096;             // 4,096
static constexpr size_t OFF_SRCS = OFF_BPRE + 4096;             // 3,200,000
static constexpr size_t OFF_NORM = OFF_SRCS + 3200000;          // 3,200,000
static constexpr size_t OFF_CS   = OFF_NORM + 3200000;          // 2,048
static constexpr size_t OFF_CB   = OFF_CS + 2048;               // 2,048

extern "C" void kernel_launch(void* const* d_in, const int* in_sizes, int n_in,
                              void* d_out, int out_size, void* d_ws, size_t ws_size,
                              hipStream_t stream) {
    const float* X = (const float*)d_in[0];
    const int* EI = (const int*)d_in[1];      // int32 per harness contract
    const float* W = (const float*)d_in[2];
    const float* B = (const float*)d_in[3];
    const float* G = (const float*)d_in[4];
    const float* BE = (const float*)d_in[5];
    const float* RM = (const float*)d_in[6];
    const float* RV = (const float*)d_in[7];
    float* out = (float*)d_out;
    char* ws = (char*)d_ws;

    ushort* H = (ushort*)(ws + OFF_H);
    ushort* WT = (ushort*)(ws + OFF_WT);
    int* cnt = (int*)(ws + OFF_CNT);
    float* dis = (float*)(ws + OFF_DIS);
    int* offs = (int*)(ws + OFF_OFFS);
    int* cursor = (int*)(ws + OFF_CUR);
    int* bsum = (int*)(ws + OFF_BSUM);
    int* bpre = (int*)(ws + OFF_BPRE);
    int* srcs = (int*)(ws + OFF_SRCS);
    float* norms = (float*)(ws + OFF_NORM);
    float* cscale = (float*)(ws + OFF_CS);
    float* cbias = (float*)(ws + OFF_CB);

    hipMemsetAsync(cnt, 0, NN * sizeof(int), stream);
    hipMemsetAsync(cursor, 0, NN * sizeof(int), stream);

    wt_convert<<<(DIM * DIM) / 256, 256, 0, stream>>>(W, WT);
    bn_prep<<<2, 256, 0, stream>>>(B, G, BE, RM, RV, cscale, cbias);
    deg_count<<<(NE + 255) / 256, 256, 0, stream>>>(EI, cnt);
    dis_kernel<<<(NN + 255) / 256, 256, 0, stream>>>(cnt, dis);
    scan1<<<NB_SCAN, 256, 0, stream>>>(cnt, bsum);
    scan2<<<1, 512, 0, stream>>>(bsum, bpre);
    scan3<<<NB_SCAN, 256, 0, stream>>>(cnt, bpre, offs);
    edge_scatter<<<(NE + 255) / 256, 256, 0, stream>>>(EI, offs, cursor, dis, srcs, norms);
    gemm_xw<<<dim3(DIM / BN, (NN + BM - 1) / BM), 256, 0, stream>>>(X, WT, H);
    aggregate<<<(NN + 3) / 4, 256, 0, stream>>>(H, srcs, norms, offs, cnt, dis, cscale, cbias, out);
}